// Round 1
// baseline (10066.579 us; speedup 1.0000x reference)
//
#include <hip/hip_runtime.h>
#include <math.h>

#define NN 1024      // N
#define NB 32        // panel width
#define TT 128       // trailing tile
#define NT 256       // threads per chol block
#define NSAMP 64     // n_mc

#define CCONST  (-0.91893853320467274f)   // -0.5*log(2*pi)
#define LOG2PI  (1.8378770664093453f)

__device__ __forceinline__ float softplus_d(float v) {
    return (v > 20.f ? v : log1pf(expf(v))) + 1e-7f;
}
__device__ __forceinline__ float log_normal_f(float v, float mean, float s, float eps) {
    float d = v - mean;
    return -d * d / (2.f * s * s + eps) - logf(s) + CCONST;
}
__device__ __forceinline__ float log_lognormal_f(float v, float mean, float s) {
    float lv = logf(v);
    float d = lv - mean;
    return -d * d / (2.f * s * s + 1e-6f) - lv - logf(s) + CCONST;
}
__device__ __forceinline__ void fma4(float4& c, float a, const float4& b) {
    c.x = fmaf(a, b.x, c.x); c.y = fmaf(a, b.y, c.y);
    c.z = fmaf(a, b.z, c.z); c.w = fmaf(a, b.w, c.w);
}

// ---------------- per-sample scalars ----------------
// scal layout (floats): [0:64) sigma2, [64:128) eta, [128:192) 1/lsZ,
// [192:256) 1/lsN, [256:320) beta, [320:384) log_prior - log_q
__global__ void scal_kernel(const float* __restrict__ z,
    const float* qbm, const float* qbs, const float* qsm, const float* qss,
    const float* qem, const float* qes, const float* qzm, const float* qzs,
    const float* qnm, const float* qns, float* __restrict__ scal)
{
    int m = threadIdx.x;
    if (m >= NSAMP) return;
    float z0 = z[m*5+0], z1 = z[m*5+1], z2 = z[m*5+2], z3 = z[m*5+3], z4 = z[m*5+4];
    float spb = softplus_d(qbs[0]);
    float sps = softplus_d(qss[0]);
    float spe = softplus_d(qes[0]);
    float spz = softplus_d(qzs[0]);
    float spn = softplus_d(qns[0]);
    float sigma2 = expf(z0 * sps + qsm[0]);
    float beta   = z1 * spb + qbm[0];
    float eta    = expf(z2 * spe + qem[0]);
    float lsZ    = expf(z3 * spz + qzm[0]);
    float lsN    = expf(z4 * spn + qnm[0]);
    float s0 = softplus_d(sqrtf(logf(2.f)));   // default prior scale
    float lp = log_normal_f(beta, 0.f, 1.f, 1e-5f)
             + log_lognormal_f(sigma2, 1.f, s0)
             + log_lognormal_f(eta,    1.f, s0)
             + log_lognormal_f(lsZ,    1.f, s0)
             + log_lognormal_f(lsN,    1.f, s0);
    float lq = log_normal_f(beta, qbm[0], spb, 1e-5f)
             + log_lognormal_f(sigma2, qsm[0], sps)
             + log_lognormal_f(eta,    qem[0], spe)
             + log_lognormal_f(lsZ,    qzm[0], spz)
             + log_lognormal_f(lsN,    qnm[0], spn);
    scal[m]           = sigma2;
    scal[NSAMP + m]   = eta;
    scal[2*NSAMP + m] = 1.f / lsZ;
    scal[3*NSAMP + m] = 1.f / lsN;
    scal[4*NSAMP + m] = beta;
    scal[5*NSAMP + m] = lp - lq;
}

// ---------------- covariance build (lower triangle only) ----------------
__global__ __launch_bounds__(256)
void cov_kernel(float* __restrict__ cov, const float* __restrict__ scal,
                const float* __restrict__ x, int mbase)
{
    int i  = blockIdx.x;     // row
    int ml = blockIdx.y;     // chunk-local sample
    int m  = mbase + ml;
    float sigma2 = scal[m];
    float eta    = scal[NSAMP + m];
    float ilZ    = scal[2*NSAMP + m];
    float ilN    = scal[3*NSAMP + m];
    float xi0 = x[2*i]   * ilZ;
    float xi1 = x[2*i+1] * ilN;
    float* row = cov + (size_t)ml * NN * NN + (size_t)i * NN;
    int j0 = threadIdx.x * 4;
    if (j0 > i) return;                      // only lower triangle needed
    float4 xa = *(const float4*)(x + 2*j0);
    float4 xb = *(const float4*)(x + 2*j0 + 4);
    float v[4]; float d0, d1;
    d0 = xa.x*ilZ - xi0; d1 = xa.y*ilN - xi1; v[0] = eta*__expf(-0.5f*(d0*d0+d1*d1));
    d0 = xa.z*ilZ - xi0; d1 = xa.w*ilN - xi1; v[1] = eta*__expf(-0.5f*(d0*d0+d1*d1));
    d0 = xb.x*ilZ - xi0; d1 = xb.y*ilN - xi1; v[2] = eta*__expf(-0.5f*(d0*d0+d1*d1));
    d0 = xb.z*ilZ - xi0; d1 = xb.w*ilN - xi1; v[3] = eta*__expf(-0.5f*(d0*d0+d1*d1));
    #pragma unroll
    for (int q = 0; q < 4; ++q) if (j0 + q == i) v[q] += sigma2;
    if (j0 + 3 <= i) {
        float4 o; o.x = v[0]; o.y = v[1]; o.z = v[2]; o.w = v[3];
        *(float4*)(row + j0) = o;
    } else {
        #pragma unroll
        for (int q = 0; q < 4; ++q) if (j0 + q <= i) row[j0+q] = v[q];
    }
}

// ---------------- per-sample blocked Cholesky + fused forward solve ----------------
__global__ __launch_bounds__(NT)
void chol_kernel(float* __restrict__ covb, const float* __restrict__ scal,
                 const float* __restrict__ y, float* __restrict__ out, int mbase)
{
    int m = mbase + blockIdx.x;
    float* C = covb + (size_t)blockIdx.x * NN * NN;

    __shared__ float T[NB][NB+1];                 // diagonal triangle block
    __shared__ float rs_s[NB];                    // 1/sqrt(d_j) == 1/L(j,j)
    __shared__ float sol_s[NB];                   // solved chunk of forward solve
    __shared__ float bvec[NN];                    // running RHS (y - beta)
    __shared__ __align__(16) float As[NB][TT+4];  // k-major panel slice (i side)
    __shared__ __align__(16) float Bs[NB][TT+4];  // k-major panel slice (j side)
    __shared__ float s_quad, s_ld;

    int tid = threadIdx.x;
    {
        float beta = scal[4*NSAMP + m];
        for (int r = tid; r < NN; r += NT) bvec[r] = y[r] - beta;
    }
    if (tid == 0) { s_quad = 0.f; s_ld = 0.f; }
    __syncthreads();

    for (int p = 0; p < NN; p += NB) {
        // ---- 1. load 32x32 diagonal block ----
        for (int idx = tid; idx < NB*NB; idx += NT) {
            int r = idx >> 5, c = idx & 31;
            T[r][c] = C[(size_t)(p + r) * NN + (p + c)];
        }
        __syncthreads();

        // ---- 2. wave 0: factor triangle (raw form), solve b chunk, stats, scale ----
        if (tid < 64) {
            int lane = tid;
            for (int j = 0; j < NB; ++j) {
                float d = fmaxf(T[j][j], 1e-30f);
                float inv = 1.f / d;
                if (lane > j && lane < NB) {
                    int r = lane;
                    float mult = T[r][j] * inv;
                    for (int c = j + 1; c < NB; ++c)
                        T[r][c] -= mult * T[c][j];
                    bvec[p + r] -= mult * bvec[p + j];
                }
            }
            float q = 0.f, ldv = 0.f;
            if (lane < NB) {
                float d = fmaxf(T[lane][lane], 1e-30f);
                float r = rsqrtf(d);
                rs_s[lane] = r;
                float sj = bvec[p + lane] * r;
                sol_s[lane] = sj;
                q = sj * sj;
                ldv = logf(d);                     // = 2*log(L_jj)
            }
            #pragma unroll
            for (int off = 16; off > 0; off >>= 1) {
                q   += __shfl_down(q, off, 32);
                ldv += __shfl_down(ldv, off, 32);
            }
            if (lane == 0) { s_quad += q; s_ld += ldv; }
            // convert raw triangle -> final L (column scale by rs)
            for (int idx = lane; idx < NB*NB; idx += 64) {
                int r = idx >> 5, c = idx & 31;
                T[r][c] *= rs_s[c];
            }
        }
        __syncthreads();

        // ---- 3. panel TRSM (rows p+NB..N-1) + RHS update ----
        for (int r0 = p + NB + tid; r0 < NN; r0 += NT) {
            float* rowp = C + (size_t)r0 * NN + p;
            float a[NB];
            #pragma unroll
            for (int c4 = 0; c4 < NB; c4 += 4) {
                float4 v = *(const float4*)(rowp + c4);
                a[c4] = v.x; a[c4+1] = v.y; a[c4+2] = v.z; a[c4+3] = v.w;
            }
            float l[NB];
            #pragma unroll
            for (int j = 0; j < NB; ++j) {
                float acc = a[j];
                #pragma unroll
                for (int c = 0; c < j; ++c)
                    acc -= l[c] * T[j][c];
                l[j] = acc * rs_s[j];
            }
            #pragma unroll
            for (int c4 = 0; c4 < NB; c4 += 4) {
                float4 v; v.x = l[c4]; v.y = l[c4+1]; v.z = l[c4+2]; v.w = l[c4+3];
                *(float4*)(rowp + c4) = v;
            }
            float bacc = 0.f;
            #pragma unroll
            for (int j = 0; j < NB; ++j) bacc += l[j] * sol_s[j];
            bvec[r0] -= bacc;
        }
        __threadfence();
        __syncthreads();

        // ---- 4. trailing SYRK: C[i,j] -= sum_k L[i,k]*L[j,k] ----
        int Tr = NN - p - NB;
        int ntile = (Tr + TT - 1) / TT;
        int tx = tid & 31, ty = tid >> 5;
        int tx4 = tx * 4, ty16 = ty * 16;
        for (int ti = 0; ti < ntile; ++ti) {
            for (int tj = 0; tj <= ti; ++tj) {
                int ibase = p + NB + ti * TT;
                int jbase = p + NB + tj * TT;
                // stage panel slices k-major into LDS
                for (int idx = tid; idx < TT * (NB/4); idx += NT) {
                    int ii = idx >> 3;
                    int c4 = (idx & 7) << 2;
                    int gr = ibase + ii;
                    float4 v = make_float4(0.f, 0.f, 0.f, 0.f);
                    if (gr < NN) v = *(const float4*)(C + (size_t)gr * NN + p + c4);
                    As[c4][ii] = v.x; As[c4+1][ii] = v.y; As[c4+2][ii] = v.z; As[c4+3][ii] = v.w;
                }
                if (tj != ti) {
                    for (int idx = tid; idx < TT * (NB/4); idx += NT) {
                        int ii = idx >> 3;
                        int c4 = (idx & 7) << 2;
                        int gr = jbase + ii;
                        float4 v = make_float4(0.f, 0.f, 0.f, 0.f);
                        if (gr < NN) v = *(const float4*)(C + (size_t)gr * NN + p + c4);
                        Bs[c4][ii] = v.x; Bs[c4+1][ii] = v.y; Bs[c4+2][ii] = v.z; Bs[c4+3][ii] = v.w;
                    }
                }
                __syncthreads();
                const float (*Bp)[TT+4] = (tj == ti) ? As : Bs;

                float4 acc[16];
                #pragma unroll
                for (int r = 0; r < 16; ++r) acc[r] = make_float4(0.f, 0.f, 0.f, 0.f);
                #pragma unroll 4
                for (int k = 0; k < NB; ++k) {
                    float4 bv = *(const float4*)&Bp[k][tx4];
                    #pragma unroll
                    for (int qq = 0; qq < 4; ++qq) {
                        float4 av = *(const float4*)&As[k][ty16 + 4*qq];
                        fma4(acc[4*qq+0], av.x, bv);
                        fma4(acc[4*qq+1], av.y, bv);
                        fma4(acc[4*qq+2], av.z, bv);
                        fma4(acc[4*qq+3], av.w, bv);
                    }
                }
                int jcol = jbase + tx4;
                if (jcol < NN) {
                    #pragma unroll
                    for (int rr = 0; rr < 16; ++rr) {
                        int g = ibase + ty16 + rr;
                        if (g < NN) {
                            float4* cp = (float4*)(C + (size_t)g * NN + jcol);
                            float4 cur = *cp;
                            cur.x -= acc[rr].x; cur.y -= acc[rr].y;
                            cur.z -= acc[rr].z; cur.w -= acc[rr].w;
                            *cp = cur;
                        }
                    }
                }
                __syncthreads();
            }
        }
        __threadfence();
    }

    __syncthreads();
    if (tid == 0)
        out[m] = -0.5f * (s_quad + s_ld + (float)NN * LOG2PI) + scal[5*NSAMP + m];
}

extern "C" void kernel_launch(void* const* d_in, const int* in_sizes, int n_in,
                              void* d_out, int out_size, void* d_ws, size_t ws_size,
                              hipStream_t stream)
{
    const float* x   = (const float*)d_in[0];
    const float* y   = (const float*)d_in[1];
    const float* z   = (const float*)d_in[2];
    const float* qbm = (const float*)d_in[3];
    const float* qbs = (const float*)d_in[4];
    const float* qsm = (const float*)d_in[5];
    const float* qss = (const float*)d_in[6];
    const float* qem = (const float*)d_in[7];
    const float* qes = (const float*)d_in[8];
    const float* qzm = (const float*)d_in[9];
    const float* qzs = (const float*)d_in[10];
    const float* qnm = (const float*)d_in[11];
    const float* qns = (const float*)d_in[12];
    float* out  = (float*)d_out;
    float* ws   = (float*)d_ws;
    float* scal = ws;
    float* cov  = ws + 1024;   // 4KB-aligned offset for the covariance buffers

    scal_kernel<<<1, 64, 0, stream>>>(z, qbm, qbs, qsm, qss, qem, qes, qzm, qzs, qnm, qns, scal);

    // chunk samples if workspace can't hold all 64 matrices (64*4MB + 4KB)
    size_t availF = ws_size / 4;
    size_t perM   = (size_t)NN * NN;
    int mc_max = NSAMP;
    if (availF < 1024 + (size_t)NSAMP * perM) {
        size_t rem = (availF > 1024) ? (availF - 1024) : 0;
        mc_max = (int)(rem / perM);
        if (mc_max < 1) mc_max = 1;
        if (mc_max > NSAMP) mc_max = NSAMP;
    }
    for (int mb = 0; mb < NSAMP; mb += mc_max) {
        int mc = NSAMP - mb; if (mc > mc_max) mc = mc_max;
        cov_kernel<<<dim3(NN, mc), 256, 0, stream>>>(cov, scal, x, mb);
        chol_kernel<<<mc, NT, 0, stream>>>(cov, scal, y, out, mb);
    }
}

// Round 2
// 5258.631 us; speedup vs baseline: 1.9143x; 1.9143x over previous
//
#include <hip/hip_runtime.h>
#include <math.h>

#define NN 1024      // N
#define NB 64        // panel width
#define TT 128       // trailing SYRK tile
#define NSAMP 64     // n_mc

#define CCONST  (-0.91893853320467274f)   // -0.5*log(2*pi)
#define LOG2PI  (1.8378770664093453f)

__device__ __forceinline__ float bcastf(float v, int lane) {
    return __int_as_float(__builtin_amdgcn_readlane(__float_as_int(v), lane));
}
__device__ __forceinline__ float softplus_d(float v) {
    return (v > 20.f ? v : log1pf(expf(v))) + 1e-7f;
}
__device__ __forceinline__ float log_normal_f(float v, float mean, float s, float eps) {
    float d = v - mean;
    return -d * d / (2.f * s * s + eps) - logf(s) + CCONST;
}
__device__ __forceinline__ float log_lognormal_f(float v, float mean, float s) {
    float lv = logf(v);
    float d = lv - mean;
    return -d * d / (2.f * s * s + 1e-6f) - lv - logf(s) + CCONST;
}
__device__ __forceinline__ void fma4(float4& c, float a, const float4& b) {
    c.x = fmaf(a, b.x, c.x); c.y = fmaf(a, b.y, c.y);
    c.z = fmaf(a, b.z, c.z); c.w = fmaf(a, b.w, c.w);
}

// ---------------- per-sample scalars ----------------
// scal layout (floats): [0:64) sigma2, [64:128) eta, [128:192) 1/lsZ,
// [192:256) 1/lsN, [256:320) beta, [320:384) log_prior - log_q
__global__ void scal_kernel(const float* __restrict__ z,
    const float* qbm, const float* qbs, const float* qsm, const float* qss,
    const float* qem, const float* qes, const float* qzm, const float* qzs,
    const float* qnm, const float* qns, float* __restrict__ scal)
{
    int m = threadIdx.x;
    if (m >= NSAMP) return;
    float z0 = z[m*5+0], z1 = z[m*5+1], z2 = z[m*5+2], z3 = z[m*5+3], z4 = z[m*5+4];
    float spb = softplus_d(qbs[0]);
    float sps = softplus_d(qss[0]);
    float spe = softplus_d(qes[0]);
    float spz = softplus_d(qzs[0]);
    float spn = softplus_d(qns[0]);
    float sigma2 = expf(z0 * sps + qsm[0]);
    float beta   = z1 * spb + qbm[0];
    float eta    = expf(z2 * spe + qem[0]);
    float lsZ    = expf(z3 * spz + qzm[0]);
    float lsN    = expf(z4 * spn + qnm[0]);
    float s0 = softplus_d(sqrtf(logf(2.f)));
    float lp = log_normal_f(beta, 0.f, 1.f, 1e-5f)
             + log_lognormal_f(sigma2, 1.f, s0)
             + log_lognormal_f(eta,    1.f, s0)
             + log_lognormal_f(lsZ,    1.f, s0)
             + log_lognormal_f(lsN,    1.f, s0);
    float lq = log_normal_f(beta, qbm[0], spb, 1e-5f)
             + log_lognormal_f(sigma2, qsm[0], sps)
             + log_lognormal_f(eta,    qem[0], spe)
             + log_lognormal_f(lsZ,    qzm[0], spz)
             + log_lognormal_f(lsN,    qnm[0], spn);
    scal[m]           = sigma2;
    scal[NSAMP + m]   = eta;
    scal[2*NSAMP + m] = 1.f / lsZ;
    scal[3*NSAMP + m] = 1.f / lsN;
    scal[4*NSAMP + m] = beta;
    scal[5*NSAMP + m] = lp - lq;
}

// ---------------- covariance build (lower triangle) + bvec/stats init ----------------
__global__ __launch_bounds__(256)
void cov_kernel(float* __restrict__ cov, const float* __restrict__ scal,
                const float* __restrict__ x, const float* __restrict__ y,
                float* __restrict__ bvec, float* __restrict__ stats, int mbase)
{
    int i  = blockIdx.x;     // row
    int ml = blockIdx.y;     // chunk-local sample
    int m  = mbase + ml;
    if (threadIdx.x == 0) {
        bvec[(size_t)m * NN + i] = y[i] - scal[4*NSAMP + m];
        if (i == 0) { stats[2*m] = 0.f; stats[2*m+1] = 0.f; }
    }
    float sigma2 = scal[m];
    float eta    = scal[NSAMP + m];
    float ilZ    = scal[2*NSAMP + m];
    float ilN    = scal[3*NSAMP + m];
    float xi0 = x[2*i]   * ilZ;
    float xi1 = x[2*i+1] * ilN;
    float* row = cov + (size_t)ml * NN * NN + (size_t)i * NN;
    int j0 = threadIdx.x * 4;
    if (j0 > i) return;                      // only lower triangle needed
    float4 xa = *(const float4*)(x + 2*j0);
    float4 xb = *(const float4*)(x + 2*j0 + 4);
    float v[4]; float d0, d1;
    d0 = xa.x*ilZ - xi0; d1 = xa.y*ilN - xi1; v[0] = eta*__expf(-0.5f*(d0*d0+d1*d1));
    d0 = xa.z*ilZ - xi0; d1 = xa.w*ilN - xi1; v[1] = eta*__expf(-0.5f*(d0*d0+d1*d1));
    d0 = xb.x*ilZ - xi0; d1 = xb.y*ilN - xi1; v[2] = eta*__expf(-0.5f*(d0*d0+d1*d1));
    d0 = xb.z*ilZ - xi0; d1 = xb.w*ilN - xi1; v[3] = eta*__expf(-0.5f*(d0*d0+d1*d1));
    #pragma unroll
    for (int q = 0; q < 4; ++q) if (j0 + q == i) v[q] += sigma2;
    if (j0 + 3 <= i) {
        float4 o; o.x = v[0]; o.y = v[1]; o.z = v[2]; o.w = v[3];
        *(float4*)(row + j0) = o;
    } else {
        #pragma unroll
        for (int q = 0; q < 4; ++q) if (j0 + q <= i) row[j0+q] = v[q];
    }
}

// ---------------- panel factor + TRSM + fused forward solve ----------------
// one block per sample; wave 0 factors the 64x64 diag block entirely in
// registers (lane r holds row r; pivot broadcasts via v_readlane), then all
// 512 threads TRSM the rows below and update the RHS vector.
__global__ __launch_bounds__(512)
void fact_kernel(float* __restrict__ covb, float* __restrict__ bvec,
                 float* __restrict__ stats, const float* __restrict__ scal,
                 float* __restrict__ out, int mbase, int p)
{
    int ml = blockIdx.x, m = mbase + ml;
    float* C = covb + (size_t)ml * NN * NN;
    __shared__ __align__(16) float Tl[NB][68];   // final L11 (row-major, padded)
    __shared__ float rs_s[NB], sol_s[NB], s_quad;
    int tid = threadIdx.x;

    if (tid < 64) {
        int r = tid;
        float row[NB];
        const float* src = C + (size_t)(p + r) * NN + p;
        #pragma unroll
        for (int q = 0; q < NB/4; ++q) {
            float4 v = *(const float4*)(src + 4*q);
            row[4*q+0] = v.x; row[4*q+1] = v.y; row[4*q+2] = v.z; row[4*q+3] = v.w;
        }
        float b = bvec[(size_t)m * NN + p + r];
        float quad_add = 0.f;
        #pragma unroll
        for (int j = 0; j < NB; ++j) {
            float dj = fmaxf(bcastf(row[j], j), 1e-30f);
            float rs = rsqrtf(dj);
            row[j] *= rs;                         // now row[j] = L[r][j] (r>=j)
            float sj = bcastf(b, j) * rs;         // forward-solve pivot
            quad_add = fmaf(sj, sj, quad_add);
            b = fmaf(-row[j], sj, b);
            if (r == j) { rs_s[j] = rs; sol_s[j] = sj; }
            #pragma unroll
            for (int c = j + 1; c < NB; ++c) {
                float s = bcastf(row[j], c);      // = L[c][j]
                row[c] = fmaf(-row[j], s, row[c]);
            }
        }
        #pragma unroll
        for (int q = 0; q < NB/4; ++q) {
            float4 v; v.x = row[4*q]; v.y = row[4*q+1]; v.z = row[4*q+2]; v.w = row[4*q+3];
            *(float4*)&Tl[r][4*q] = v;
        }
        if (r == 0) s_quad = quad_add;
    }
    __syncthreads();

    // wave 1: logdet reduction + stats update (+ final output on last panel)
    if (tid >= 64 && tid < 128) {
        float lv = logf(rs_s[tid - 64]);          // log(1/L_jj)
        #pragma unroll
        for (int off = 32; off > 0; off >>= 1) lv += __shfl_down(lv, off);
        if (tid == 64) {
            float qt = stats[2*m] + s_quad;
            float lt = stats[2*m+1] - 2.f * lv;   // += sum log(d_j)
            stats[2*m] = qt; stats[2*m+1] = lt;
            if (p == NN - NB)
                out[m] = -0.5f * (qt + lt + (float)NN * LOG2PI) + scal[5*NSAMP + m];
        }
    }

    // panel TRSM: rows p+NB..N-1, in place; also RHS update
    for (int r0 = p + NB + tid; r0 < NN; r0 += 512) {
        float* rowp = C + (size_t)r0 * NN + p;
        float l[NB];
        #pragma unroll
        for (int q = 0; q < NB/4; ++q) {
            float4 v = *(const float4*)(rowp + 4*q);
            l[4*q] = v.x; l[4*q+1] = v.y; l[4*q+2] = v.z; l[4*q+3] = v.w;
        }
        #pragma unroll
        for (int j = 0; j < NB; ++j) {
            float acc = l[j];
            #pragma unroll
            for (int c = 0; c < j; ++c) acc = fmaf(-l[c], Tl[j][c], acc);
            l[j] = acc * rs_s[j];
        }
        #pragma unroll
        for (int q = 0; q < NB/4; ++q) {
            float4 v; v.x = l[4*q]; v.y = l[4*q+1]; v.z = l[4*q+2]; v.w = l[4*q+3];
            *(float4*)(rowp + 4*q) = v;
        }
        float bacc = 0.f;
        #pragma unroll
        for (int j = 0; j < NB; ++j) bacc = fmaf(l[j], sol_s[j], bacc);
        bvec[(size_t)m * NN + r0] -= bacc;
    }
}

// ---------------- trailing SYRK: C[i,j] -= sum_k L[i,k] L[j,k] ----------------
// grid (tile-pairs, samples); 128x128 tile per block, 8x8 per thread,
// K=64 staged in two 32-halves (LDS 33.8KB -> 4 blocks/CU).
__global__ __launch_bounds__(256)
void syrk_kernel(float* __restrict__ covb, int p)
{
    int ml = blockIdx.y;
    float* C = covb + (size_t)ml * NN * NN;
    int pair = blockIdx.x;
    int ti = (int)((sqrtf(8.f * pair + 1.f) - 1.f) * 0.5f);
    while ((ti + 1) * (ti + 2) / 2 <= pair) ++ti;
    while (ti * (ti + 1) / 2 > pair) --ti;
    int tj = pair - ti * (ti + 1) / 2;
    int base = p + NB;
    int ibase = base + ti * TT, jbase = base + tj * TT;

    __shared__ __align__(16) float As[32][TT+4];
    __shared__ __align__(16) float Bs[32][TT+4];
    int tid = threadIdx.x;
    int tx = tid & 15, ty = tid >> 4;
    int c0 = tx * 8, r0g = ty * 8;

    float4 acc[8][2];
    #pragma unroll
    for (int r = 0; r < 8; ++r) { acc[r][0] = make_float4(0,0,0,0); acc[r][1] = make_float4(0,0,0,0); }

    #pragma unroll
    for (int ks = 0; ks < NB; ks += 32) {
        // stage k-half, k-major
        for (int idx = tid; idx < TT * 8; idx += 256) {
            int ii = idx >> 3;
            int c4 = (idx & 7) << 2;
            int gr = ibase + ii;
            float4 v = make_float4(0,0,0,0);
            if (gr < NN) v = *(const float4*)(C + (size_t)gr * NN + p + ks + c4);
            As[c4][ii] = v.x; As[c4+1][ii] = v.y; As[c4+2][ii] = v.z; As[c4+3][ii] = v.w;
        }
        if (ti != tj) {
            for (int idx = tid; idx < TT * 8; idx += 256) {
                int ii = idx >> 3;
                int c4 = (idx & 7) << 2;
                int gr = jbase + ii;
                float4 v = make_float4(0,0,0,0);
                if (gr < NN) v = *(const float4*)(C + (size_t)gr * NN + p + ks + c4);
                Bs[c4][ii] = v.x; Bs[c4+1][ii] = v.y; Bs[c4+2][ii] = v.z; Bs[c4+3][ii] = v.w;
            }
        }
        __syncthreads();
        const float (*Bp)[TT+4] = (ti == tj) ? As : Bs;
        #pragma unroll
        for (int k = 0; k < 32; ++k) {
            float4 b0 = *(const float4*)&Bp[k][c0];
            float4 b1 = *(const float4*)&Bp[k][c0 + 4];
            float4 a0 = *(const float4*)&As[k][r0g];
            float4 a1 = *(const float4*)&As[k][r0g + 4];
            float ar[8] = {a0.x, a0.y, a0.z, a0.w, a1.x, a1.y, a1.z, a1.w};
            #pragma unroll
            for (int r = 0; r < 8; ++r) {
                fma4(acc[r][0], ar[r], b0);
                fma4(acc[r][1], ar[r], b1);
            }
        }
        __syncthreads();
    }

    int jcol = jbase + c0;
    #pragma unroll
    for (int r = 0; r < 8; ++r) {
        int g = ibase + r0g + r;
        if (g < NN) {
            float* cp = C + (size_t)g * NN + jcol;
            if (jcol + 7 < NN) {
                float4 u0 = *(float4*)cp;
                float4 u1 = *((float4*)cp + 1);
                u0.x -= acc[r][0].x; u0.y -= acc[r][0].y; u0.z -= acc[r][0].z; u0.w -= acc[r][0].w;
                u1.x -= acc[r][1].x; u1.y -= acc[r][1].y; u1.z -= acc[r][1].z; u1.w -= acc[r][1].w;
                *(float4*)cp = u0;
                *((float4*)cp + 1) = u1;
            } else {
                float av[8] = {acc[r][0].x, acc[r][0].y, acc[r][0].z, acc[r][0].w,
                               acc[r][1].x, acc[r][1].y, acc[r][1].z, acc[r][1].w};
                #pragma unroll
                for (int q = 0; q < 8; ++q)
                    if (jcol + q < NN) cp[q] -= av[q];
            }
        }
    }
}

extern "C" void kernel_launch(void* const* d_in, const int* in_sizes, int n_in,
                              void* d_out, int out_size, void* d_ws, size_t ws_size,
                              hipStream_t stream)
{
    const float* x   = (const float*)d_in[0];
    const float* y   = (const float*)d_in[1];
    const float* z   = (const float*)d_in[2];
    const float* qbm = (const float*)d_in[3];
    const float* qbs = (const float*)d_in[4];
    const float* qsm = (const float*)d_in[5];
    const float* qss = (const float*)d_in[6];
    const float* qem = (const float*)d_in[7];
    const float* qes = (const float*)d_in[8];
    const float* qzm = (const float*)d_in[9];
    const float* qzs = (const float*)d_in[10];
    const float* qnm = (const float*)d_in[11];
    const float* qns = (const float*)d_in[12];
    float* out  = (float*)d_out;
    float* ws   = (float*)d_ws;

    // workspace layout (floats)
    float* scal  = ws;                       // 384 used, 1024 reserved
    float* bvec  = ws + 1024;                // 64 * 1024
    float* stats = ws + 1024 + NSAMP*NN;     // 128 used, 512 reserved
    float* cov   = ws + 1024 + NSAMP*NN + 512;
    size_t headF = 1024 + (size_t)NSAMP*NN + 512;

    scal_kernel<<<1, 64, 0, stream>>>(z, qbm, qbs, qsm, qss, qem, qes, qzm, qzs, qnm, qns, scal);

    size_t availF = ws_size / 4;
    size_t perM   = (size_t)NN * NN;
    int mc_max = NSAMP;
    if (availF < headF + (size_t)NSAMP * perM) {
        size_t rem = (availF > headF) ? (availF - headF) : 0;
        mc_max = (int)(rem / perM);
        if (mc_max < 1) mc_max = 1;
        if (mc_max > NSAMP) mc_max = NSAMP;
    }

    for (int mb = 0; mb < NSAMP; mb += mc_max) {
        int mc = NSAMP - mb; if (mc > mc_max) mc = mc_max;
        cov_kernel<<<dim3(NN, mc), 256, 0, stream>>>(cov, scal, x, y, bvec, stats, mb);
        for (int p = 0; p < NN; p += NB) {
            fact_kernel<<<mc, 512, 0, stream>>>(cov, bvec, stats, scal, out, mb, p);
            int Tr = NN - p - NB;
            if (Tr > 0) {
                int nt = (Tr + TT - 1) / TT;
                int npairs = nt * (nt + 1) / 2;
                syrk_kernel<<<dim3(npairs, mc), 256, 0, stream>>>(cov, p);
            }
        }
    }
}